// Round 12
// baseline (139.231 us; speedup 1.0000x reference)
//
#include <hip/hip_runtime.h>
#include <hip/hip_bf16.h>

typedef unsigned short u16;
typedef __bf16 bf16x8 __attribute__((ext_vector_type(8)));
typedef float f32x4 __attribute__((ext_vector_type(4)));
typedef unsigned short u16x8 __attribute__((ext_vector_type(8)));
typedef unsigned short u16x4 __attribute__((ext_vector_type(4)));

__device__ __forceinline__ float bf2f(u16 u) {
  unsigned int x = ((unsigned int)u) << 16;
  return __builtin_bit_cast(float, x);
}
__device__ __forceinline__ u16 f2bf(float f) {
  unsigned int x = __builtin_bit_cast(unsigned int, f);
  x = x + 0x7FFFu + ((x >> 16) & 1u);
  return (u16)(x >> 16);
}

// async global->LDS, 16B per lane; LDS dest is wave-uniform base + lane*16.
__device__ __forceinline__ void gload_lds16(const u16* g, u16* l) {
  __builtin_amdgcn_global_load_lds(
      (const __attribute__((address_space(1))) unsigned int*)(unsigned long long)(uintptr_t)g,
      (__attribute__((address_space(3))) unsigned int*)(unsigned int)(uintptr_t)l,
      16, 0, 0);
}

// ---------------- prep: cast X fp32->bf16  UNION  transpose+cast W ----------------
__global__ __launch_bounds__(256) void prep_kernel(const float* __restrict__ X,
                                                   const float* __restrict__ Wq,
                                                   const float* __restrict__ Wk,
                                                   const float* __restrict__ Wv,
                                                   u16* __restrict__ Xb,
                                                   u16* __restrict__ Wt) {
  const int id = blockIdx.x;
  const int tid = threadIdx.x;
  if (id < 4096) {
    long i = ((long)id * 256 + tid) * 8;
    float4 a = *reinterpret_cast<const float4*>(X + i);
    float4 b = *reinterpret_cast<const float4*>(X + i + 4);
    u16x8 o;
    o[0] = f2bf(a.x); o[1] = f2bf(a.y); o[2] = f2bf(a.z); o[3] = f2bf(a.w);
    o[4] = f2bf(b.x); o[5] = f2bf(b.y); o[6] = f2bf(b.z); o[7] = f2bf(b.w);
    *reinterpret_cast<u16x8*>(Xb + i) = o;
    return;
  }
  __shared__ u16 t[64][72];
  const int id2 = id - 4096;
  const int z = id2 >> 8;
  const float* W = (z == 0) ? Wq : (z == 1) ? Wk : Wv;
  const float scale = (z == 0) ? (1.0f / 32.0f) : 1.0f;  // fold 1/sqrt(1024) into Wq
  u16* out = Wt + (long)z * 1048576;
  const int c0 = (id2 & 15) * 64;
  const int r0 = ((id2 >> 4) & 15) * 64;
#pragma unroll
  for (int i = 0; i < 4; ++i) {
    int slot = tid + 256 * i;
    int lr = slot >> 4;
    int lc4 = slot & 15;
    float4 v = *reinterpret_cast<const float4*>(W + (long)(r0 + lr) * 1024 + c0 + lc4 * 4);
    t[lr][lc4 * 4 + 0] = f2bf(v.x * scale);
    t[lr][lc4 * 4 + 1] = f2bf(v.y * scale);
    t[lr][lc4 * 4 + 2] = f2bf(v.z * scale);
    t[lr][lc4 * 4 + 3] = f2bf(v.w * scale);
  }
  __syncthreads();
#pragma unroll
  for (int i = 0; i < 2; ++i) {
    int slot = tid + 256 * i;
    int orow = slot >> 3;
    int oc = slot & 7;
    u16x8 o;
#pragma unroll
    for (int j = 0; j < 8; ++j) o[j] = t[oc * 8 + j][orow];
    *reinterpret_cast<u16x8*>(out + (long)(c0 + orow) * 1024 + r0 + oc * 8) = o;
  }
}

// ---------------- fused QKV projection, 128x192 tile (r11, unchanged) ----------------
__global__ __launch_bounds__(512, 4) void gemm_qkv(const u16* __restrict__ Xb,
                                                   const u16* __restrict__ Wt,
                                                   u16* __restrict__ Qb,
                                                   u16* __restrict__ Vt) {
  const int id = blockIdx.x;            // 0..1023
  const int xcd = id & 7, j = id >> 3;  // j: 0..127
  const int bn = (xcd & 1) * 8 + (j & 7);        // 0..15
  const int bm = ((xcd >> 1) << 4) + (j >> 3);   // 0..63
  const int m0 = bm * 128, n0 = bn * 192;
  const int K = 1024;

  __shared__ u16 ldsA[2][8192];    // 128 x 64
  __shared__ u16 ldsB[2][12288];   // 192 x 64

  const int tid = threadIdx.x;          // 0..511
  const int lane = tid & 63;
  const int wid = tid >> 6;             // 0..7
  const int wm = wid >> 2, wn = wid & 3;
  const int l16 = lane & 15, lh = lane >> 4;
  const int strow = tid >> 3;                       // 0..63
  const int scol = ((tid & 7) ^ (strow & 7)) * 8;   // pre-swizzled source col
  const int rsw = l16 & 7;                          // read-side swizzle key

  f32x4 acc[4][3];
#pragma unroll
  for (int mi = 0; mi < 4; ++mi)
#pragma unroll
    for (int ni = 0; ni < 3; ++ni) acc[mi][ni] = (f32x4)(0.0f);

  auto stage = [&](int d, int k0) {
#pragma unroll
    for (int l = 0; l < 2; ++l)
      gload_lds16(Xb + (long)(m0 + l * 64 + strow) * K + k0 + scol,
                  &ldsA[d][l * 4096 + tid * 8]);
#pragma unroll
    for (int l = 0; l < 3; ++l)
      gload_lds16(Wt + (long)(n0 + l * 64 + strow) * K + k0 + scol,
                  &ldsB[d][l * 4096 + tid * 8]);
  };

  stage(0, 0);
  int cur = 0;
  for (int k0 = 0; k0 < K; k0 += 64) {
    __syncthreads();                          // buf[cur] ready; old readers done
    if (k0 + 64 < K) stage(cur ^ 1, k0 + 64); // lands during compute below
#pragma unroll
    for (int kk = 0; kk < 2; ++kk) {
      bf16x8 af[4], bfr[3];
#pragma unroll
      for (int mi = 0; mi < 4; ++mi)
        af[mi] = *reinterpret_cast<const bf16x8*>(
            &ldsA[cur][(wm * 64 + mi * 16 + l16) * 64 + (((kk * 4 + lh) ^ rsw)) * 8]);
#pragma unroll
      for (int ni = 0; ni < 3; ++ni)
        bfr[ni] = *reinterpret_cast<const bf16x8*>(
            &ldsB[cur][(wn * 48 + ni * 16 + l16) * 64 + (((kk * 4 + lh) ^ rsw)) * 8]);
#pragma unroll
      for (int mi = 0; mi < 4; ++mi)
#pragma unroll
        for (int ni = 0; ni < 3; ++ni)
          acc[mi][ni] = __builtin_amdgcn_mfma_f32_16x16x32_bf16(bfr[ni], af[mi], acc[mi][ni], 0, 0, 0);
    }
    cur ^= 1;
  }

  // Swapped layout: C[m0+wm*64+mi*16+l16][n0+wn*48+ni*16+lh*4+r] = acc[mi][ni][r]
  const int rowt = m0 + wm * 64 + l16;
#pragma unroll
  for (int ni = 0; ni < 3; ++ni) {
    const int gc0 = n0 + wn * 48 + ni * 16 + lh * 4;  // 16-col fragment never
    const int z = gc0 >> 10;                          // straddles a 1024 boundary
    const int lc = gc0 & 1023;
    if (z < 2) {
      u16* C = Qb + (long)z * 8388608;
#pragma unroll
      for (int mi = 0; mi < 4; ++mi) {
        u16x4 o;
#pragma unroll
        for (int r = 0; r < 4; ++r) o[r] = f2bf(acc[mi][ni][r]);
        *reinterpret_cast<u16x4*>(&C[(long)(rowt + mi * 16) * 1024 + lc]) = o;
      }
    } else {
      // V: Vt[b][e][t] = acc value at t = global row, e = lc + r.
#pragma unroll
      for (int mi = 0; mi < 4; ++mi) {
        const int grow = rowt + mi * 16;
        const int b = grow >> 11, t = grow & 2047;
#pragma unroll
        for (int r = 0; r < 4; ++r)
          Vt[(long)b * 2097152 + (long)(lc + r) * 2048 + t] = f2bf(acc[mi][ni][r]);
      }
    }
  }
}

// ---------------- S = exp(Q K^T) GEMM, BK=32, 3 blocks/CU (r12) ----------------
// r11 post-mortem: S's 544 equal blocks on 512 slots (2/CU) -> 32 CUs pay 3
// lifetimes, 53% slot util. Fix: BK=32 dbuf = 16KB LDS -> 3 blocks/CU (G1),
// all 544 co-resident in one pass (max 3/CU). 4 waves of 64x64 (acc[4][4]),
// 8 ds_read_b128 + 16 MFMA per K-step (32.8 FLOP/LDS-B), 32 K-steps.
// Swizzle for 32-col rows: source col (tid&3)^((row>>1)&3), read slot
// lh^((row>>1)&3) -> banks distinct per 8-lane phase (2-way only = free).
// Epilogue: P = exp(S) (0 above diag), bf16 store + row-sum atomics (r8).
__global__ __launch_bounds__(256, 3) void gemm_s(const u16* __restrict__ Qb,
                                                 const u16* __restrict__ Kb,
                                                 u16* __restrict__ Sg,
                                                 float* __restrict__ Sums) {
  const int id = blockIdx.y * 16 + blockIdx.x;  // 0..255 per batch
  const int xcd = id & 7, j = id >> 3;
  const int bn = j & 15;
  const int bm = (j >> 4) ? (15 - xcd) : xcd;   // rows (x,15-x): balanced triangle
  const int bz = blockIdx.z;
  if (bn > bm) return;
  const int K = 1024;

  const u16* A = Qb + (long)bz * 2097152;
  const u16* B = Kb + (long)bz * 2097152;
  const int m0 = bm * 128, n0 = bn * 128;

  __shared__ u16 ldsA[2][4096];   // 128 rows x 32 cols
  __shared__ u16 ldsB[2][4096];

  const int tid = threadIdx.x;          // 0..255
  const int lane = tid & 63;
  const int wid = tid >> 6;             // 0..3
  const int wm = wid >> 1, wn = wid & 1;
  const int l16 = lane & 15, lh = lane >> 4;
  const int strow = tid >> 2;                            // 0..63
  const int scol = ((tid & 3) ^ ((strow >> 1) & 3)) * 8; // pre-swizzled source col

  f32x4 acc[4][4];
#pragma unroll
  for (int mi = 0; mi < 4; ++mi)
#pragma unroll
    for (int ni = 0; ni < 4; ++ni) acc[mi][ni] = (f32x4)(0.0f);

  // stage 128x32 of A and B: 2 issues each (256 thr x 16B = 64 rows/issue)
  auto stage = [&](int d, int k0) {
#pragma unroll
    for (int l = 0; l < 2; ++l) {
      const int row = l * 64 + strow;
      gload_lds16(A + (long)(m0 + row) * K + k0 + scol, &ldsA[d][l * 2048 + tid * 8]);
      gload_lds16(B + (long)(n0 + row) * K + k0 + scol, &ldsB[d][l * 2048 + tid * 8]);
    }
  };

  stage(0, 0);
  int cur = 0;
  for (int k0 = 0; k0 < K; k0 += 32) {
    __syncthreads();                          // buf[cur] ready; old readers done
    if (k0 + 32 < K) stage(cur ^ 1, k0 + 32); // lands during compute below
    bf16x8 af[4], bfr[4];
#pragma unroll
    for (int mi = 0; mi < 4; ++mi) {
      const int row = wm * 64 + mi * 16 + l16;
      const int slot = lh ^ ((row >> 1) & 3);
      af[mi] = *reinterpret_cast<const bf16x8*>(&ldsA[cur][row * 32 + slot * 8]);
    }
#pragma unroll
    for (int ni = 0; ni < 4; ++ni) {
      const int row = wn * 64 + ni * 16 + l16;
      const int slot = lh ^ ((row >> 1) & 3);
      bfr[ni] = *reinterpret_cast<const bf16x8*>(&ldsB[cur][row * 32 + slot * 8]);
    }
#pragma unroll
    for (int mi = 0; mi < 4; ++mi)
#pragma unroll
      for (int ni = 0; ni < 4; ++ni)
        acc[mi][ni] = __builtin_amdgcn_mfma_f32_16x16x32_bf16(bfr[ni], af[mi], acc[mi][ni], 0, 0, 0);
    cur ^= 1;
  }

  // P = exp(S), zero above diagonal; row sums from bf16-rounded values so
  // numerator/denominator agree. shfl over lh then 1 atomic per 16 lanes.
  // Swapped layout: C[m0+wm*64+mi*16+l16][n0+wn*64+ni*16+lh*4+r]
  u16* C = Sg + (long)bz * 4194304;
  float* sums = Sums + (long)bz * 2048;
  const long rown = (long)(m0 + wm * 64 + l16);
  const int coln = n0 + wn * 64 + lh * 4;
#pragma unroll
  for (int mi = 0; mi < 4; ++mi) {
    const int gr = m0 + wm * 64 + l16 + mi * 16;
    float rs = 0.0f;
#pragma unroll
    for (int ni = 0; ni < 4; ++ni) {
      u16x4 o;
#pragma unroll
      for (int r = 0; r < 4; ++r) {
        const int gc = coln + ni * 16 + r;
        const float e = (gc <= gr) ? __expf(acc[mi][ni][r]) : 0.0f;
        const u16 ub = f2bf(e);
        o[r] = ub;
        rs += bf2f(ub);
      }
      *reinterpret_cast<u16x4*>(&C[(rown + mi * 16) * 2048 + coln + ni * 16]) = o;
    }
    rs += __shfl_xor(rs, 16);
    rs += __shfl_xor(rs, 32);
    if (lh == 0) atomicAdd(&sums[gr], rs);
  }
}

// ---------------- PV GEMM (r10 config, unchanged): 128x128, 8 waves ----------------
// O = P V / rowsum per batch. grid (8,16,4), kEnd=m0+128, f32 out.
__global__ __launch_bounds__(512, 2) void gemm_pv(const u16* __restrict__ Ag,
                                                  const u16* __restrict__ Bg,
                                                  float* __restrict__ Cg,
                                                  const float* __restrict__ Sums) {
  const int id = blockIdx.y * 8 + blockIdx.x;   // 0..127
  const int xcd = id & 7, j = id >> 3;
  const int bn = j & 7;
  const int bm = (j >> 3) ? (15 - xcd) : xcd;   // balanced: work ∝ bm+1
  const int bz = blockIdx.z;
  const int K = 2048;

  const u16* A = Ag + (long)bz * 4194304;
  const u16* B = Bg + (long)bz * 2097152;
  const int m0 = bm * 128, n0 = bn * 128;
  const int kEnd = m0 + 128;

  __shared__ u16 ldsA[2][8192];
  __shared__ u16 ldsB[2][8192];

  const int tid = threadIdx.x;          // 0..511
  const int lane = tid & 63;
  const int wid = tid >> 6;             // 0..7
  const int wm = wid >> 2, wn = wid & 3;
  const int l16 = lane & 15, lh = lane >> 4;
  const int strow = tid >> 3;                       // 0..63
  const int scol = ((tid & 7) ^ (strow & 7)) * 8;   // pre-swizzled source column
  const int rsw = l16 & 7;                          // read-side swizzle key

  f32x4 acc[4][2];
#pragma unroll
  for (int mi = 0; mi < 4; ++mi)
#pragma unroll
    for (int ni = 0; ni < 2; ++ni) acc[mi][ni] = (f32x4)(0.0f);

  auto stage = [&](int d, int k0) {
#pragma unroll
    for (int l = 0; l < 2; ++l) {
      const int row = l * 64 + strow;   // 0..127
      gload_lds16(A + (long)(m0 + row) * K + k0 + scol, &ldsA[d][l * 4096 + tid * 8]);
      gload_lds16(B + (long)(n0 + row) * K + k0 + scol, &ldsB[d][l * 4096 + tid * 8]);
    }
  };

  stage(0, 0);
  int cur = 0;
  for (int k0 = 0; k0 < kEnd; k0 += 64) {
    __syncthreads();                         // buf[cur] ready; old readers done
    if (k0 + 64 < kEnd) stage(cur ^ 1, k0 + 64);  // lands during compute below
#pragma unroll
    for (int kk = 0; kk < 2; ++kk) {
      bf16x8 af[4], bfr[2];
#pragma unroll
      for (int mi = 0; mi < 4; ++mi)
        af[mi] = *reinterpret_cast<const bf16x8*>(
            &ldsA[cur][(wm * 64 + mi * 16 + l16) * 64 + (((kk * 4 + lh) ^ rsw)) * 8]);
#pragma unroll
      for (int ni = 0; ni < 2; ++ni)
        bfr[ni] = *reinterpret_cast<const bf16x8*>(
            &ldsB[cur][(wn * 32 + ni * 16 + l16) * 64 + (((kk * 4 + lh) ^ rsw)) * 8]);
#pragma unroll
      for (int mi = 0; mi < 4; ++mi)
#pragma unroll
        for (int ni = 0; ni < 2; ++ni)
          acc[mi][ni] = __builtin_amdgcn_mfma_f32_16x16x32_bf16(bfr[ni], af[mi], acc[mi][ni], 0, 0, 0);
    }
    cur ^= 1;
  }

  // O = acc / rowsum
  float* C = Cg + (long)bz * 2097152;
  const float* sums = Sums + (long)bz * 2048;
  const long rown = (long)(m0 + wm * 64 + l16);
  const int coln = n0 + wn * 32 + lh * 4;
#pragma unroll
  for (int mi = 0; mi < 4; ++mi) {
    const float inv = 1.0f / sums[(int)rown + mi * 16];
#pragma unroll
    for (int ni = 0; ni < 2; ++ni) {
      f32x4 v = acc[mi][ni] * inv;
      *reinterpret_cast<f32x4*>(&C[(rown + mi * 16) * 1024 + coln + ni * 16]) = v;
    }
  }
}

extern "C" void kernel_launch(void* const* d_in, const int* in_sizes, int n_in,
                              void* d_out, int out_size, void* d_ws, size_t ws_size,
                              hipStream_t stream) {
  const float* X  = (const float*)d_in[0];
  const float* Wq = (const float*)d_in[1];
  const float* Wk = (const float*)d_in[2];
  const float* Wv = (const float*)d_in[3];

  // workspace layout (u16 elements)
  u16* Xb = (u16*)d_ws;                 // 8192*1024
  u16* Wt = Xb + 8388608;               // [3072][1024]; Wq rows pre-scaled 1/32
  u16* Qb = Wt + 3145728;               // 8192*1024 (K follows at Qb+8388608)
  u16* Kb = Qb + 8388608;               // 8192*1024
  u16* Vt = Kb + 8388608;               // [b][1024][2048]
  u16* S  = Vt + 8388608;               // [b][2048][2048] -> holds P = exp(scores)
  float* sums = (float*)(S + 16777216); // [b][2048] row sums (32 KB)

  hipMemsetAsync(sums, 0, 4 * 2048 * sizeof(float), stream);

  // cast X + transpose W (one dispatch)
  prep_kernel<<<4864, 256, 0, stream>>>(X, Wq, Wk, Wv, Xb, Wt);

  // fused QKV projection, 128x192 tile (V written transposed); 1024 blocks = 2 rounds
  gemm_qkv<<<1024, 512, 0, stream>>>(Xb, Wt, Qb, Vt);

  // P = exp(Q K^T): BK=32, 3 blocks/CU -> 544 blocks in one residency pass
  gemm_s<<<dim3(16, 16, 4), 256, 0, stream>>>(Qb, Kb, S, sums);

  // O = P V / rowsum per batch
  gemm_pv<<<dim3(8, 16, 4), 512, 0, stream>>>(S, Vt, (float*)d_out, sums);
}

// Round 13
// 132.260 us; speedup vs baseline: 1.0527x; 1.0527x over previous
//
#include <hip/hip_runtime.h>
#include <hip/hip_bf16.h>

typedef unsigned short u16;
typedef __bf16 bf16x8 __attribute__((ext_vector_type(8)));
typedef float f32x4 __attribute__((ext_vector_type(4)));
typedef unsigned short u16x8 __attribute__((ext_vector_type(8)));
typedef unsigned short u16x4 __attribute__((ext_vector_type(4)));

__device__ __forceinline__ float bf2f(u16 u) {
  unsigned int x = ((unsigned int)u) << 16;
  return __builtin_bit_cast(float, x);
}
__device__ __forceinline__ u16 f2bf(float f) {
  unsigned int x = __builtin_bit_cast(unsigned int, f);
  x = x + 0x7FFFu + ((x >> 16) & 1u);
  return (u16)(x >> 16);
}

// async global->LDS, 16B per lane; LDS dest is wave-uniform base + lane*16.
__device__ __forceinline__ void gload_lds16(const u16* g, u16* l) {
  __builtin_amdgcn_global_load_lds(
      (const __attribute__((address_space(1))) unsigned int*)(unsigned long long)(uintptr_t)g,
      (__attribute__((address_space(3))) unsigned int*)(unsigned int)(uintptr_t)l,
      16, 0, 0);
}

// ---------------- prep: cast X fp32->bf16  UNION  transpose+cast W ----------------
__global__ __launch_bounds__(256) void prep_kernel(const float* __restrict__ X,
                                                   const float* __restrict__ Wq,
                                                   const float* __restrict__ Wk,
                                                   const float* __restrict__ Wv,
                                                   u16* __restrict__ Xb,
                                                   u16* __restrict__ Wt) {
  const int id = blockIdx.x;
  const int tid = threadIdx.x;
  if (id < 4096) {
    long i = ((long)id * 256 + tid) * 8;
    float4 a = *reinterpret_cast<const float4*>(X + i);
    float4 b = *reinterpret_cast<const float4*>(X + i + 4);
    u16x8 o;
    o[0] = f2bf(a.x); o[1] = f2bf(a.y); o[2] = f2bf(a.z); o[3] = f2bf(a.w);
    o[4] = f2bf(b.x); o[5] = f2bf(b.y); o[6] = f2bf(b.z); o[7] = f2bf(b.w);
    *reinterpret_cast<u16x8*>(Xb + i) = o;
    return;
  }
  __shared__ u16 t[64][72];
  const int id2 = id - 4096;
  const int z = id2 >> 8;
  const float* W = (z == 0) ? Wq : (z == 1) ? Wk : Wv;
  const float scale = (z == 0) ? (1.0f / 32.0f) : 1.0f;  // fold 1/sqrt(1024) into Wq
  u16* out = Wt + (long)z * 1048576;
  const int c0 = (id2 & 15) * 64;
  const int r0 = ((id2 >> 4) & 15) * 64;
#pragma unroll
  for (int i = 0; i < 4; ++i) {
    int slot = tid + 256 * i;
    int lr = slot >> 4;
    int lc4 = slot & 15;
    float4 v = *reinterpret_cast<const float4*>(W + (long)(r0 + lr) * 1024 + c0 + lc4 * 4);
    t[lr][lc4 * 4 + 0] = f2bf(v.x * scale);
    t[lr][lc4 * 4 + 1] = f2bf(v.y * scale);
    t[lr][lc4 * 4 + 2] = f2bf(v.z * scale);
    t[lr][lc4 * 4 + 3] = f2bf(v.w * scale);
  }
  __syncthreads();
#pragma unroll
  for (int i = 0; i < 2; ++i) {
    int slot = tid + 256 * i;
    int orow = slot >> 3;
    int oc = slot & 7;
    u16x8 o;
#pragma unroll
    for (int j = 0; j < 8; ++j) o[j] = t[oc * 8 + j][orow];
    *reinterpret_cast<u16x8*>(out + (long)(c0 + orow) * 1024 + r0 + oc * 8) = o;
  }
}

// ---------------- fused QKV projection, 128x192 tile (r11, unchanged) ----------------
__global__ __launch_bounds__(512, 4) void gemm_qkv(const u16* __restrict__ Xb,
                                                   const u16* __restrict__ Wt,
                                                   u16* __restrict__ Qb,
                                                   u16* __restrict__ Vt) {
  const int id = blockIdx.x;            // 0..1023
  const int xcd = id & 7, j = id >> 3;  // j: 0..127
  const int bn = (xcd & 1) * 8 + (j & 7);        // 0..15
  const int bm = ((xcd >> 1) << 4) + (j >> 3);   // 0..63
  const int m0 = bm * 128, n0 = bn * 192;
  const int K = 1024;

  __shared__ u16 ldsA[2][8192];    // 128 x 64
  __shared__ u16 ldsB[2][12288];   // 192 x 64

  const int tid = threadIdx.x;          // 0..511
  const int lane = tid & 63;
  const int wid = tid >> 6;             // 0..7
  const int wm = wid >> 2, wn = wid & 3;
  const int l16 = lane & 15, lh = lane >> 4;
  const int strow = tid >> 3;                       // 0..63
  const int scol = ((tid & 7) ^ (strow & 7)) * 8;   // pre-swizzled source col
  const int rsw = l16 & 7;                          // read-side swizzle key

  f32x4 acc[4][3];
#pragma unroll
  for (int mi = 0; mi < 4; ++mi)
#pragma unroll
    for (int ni = 0; ni < 3; ++ni) acc[mi][ni] = (f32x4)(0.0f);

  auto stage = [&](int d, int k0) {
#pragma unroll
    for (int l = 0; l < 2; ++l)
      gload_lds16(Xb + (long)(m0 + l * 64 + strow) * K + k0 + scol,
                  &ldsA[d][l * 4096 + tid * 8]);
#pragma unroll
    for (int l = 0; l < 3; ++l)
      gload_lds16(Wt + (long)(n0 + l * 64 + strow) * K + k0 + scol,
                  &ldsB[d][l * 4096 + tid * 8]);
  };

  stage(0, 0);
  int cur = 0;
  for (int k0 = 0; k0 < K; k0 += 64) {
    __syncthreads();                          // buf[cur] ready; old readers done
    if (k0 + 64 < K) stage(cur ^ 1, k0 + 64); // lands during compute below
#pragma unroll
    for (int kk = 0; kk < 2; ++kk) {
      bf16x8 af[4], bfr[3];
#pragma unroll
      for (int mi = 0; mi < 4; ++mi)
        af[mi] = *reinterpret_cast<const bf16x8*>(
            &ldsA[cur][(wm * 64 + mi * 16 + l16) * 64 + (((kk * 4 + lh) ^ rsw)) * 8]);
#pragma unroll
      for (int ni = 0; ni < 3; ++ni)
        bfr[ni] = *reinterpret_cast<const bf16x8*>(
            &ldsB[cur][(wn * 48 + ni * 16 + l16) * 64 + (((kk * 4 + lh) ^ rsw)) * 8]);
#pragma unroll
      for (int mi = 0; mi < 4; ++mi)
#pragma unroll
        for (int ni = 0; ni < 3; ++ni)
          acc[mi][ni] = __builtin_amdgcn_mfma_f32_16x16x32_bf16(bfr[ni], af[mi], acc[mi][ni], 0, 0, 0);
    }
    cur ^= 1;
  }

  // Swapped layout: C[m0+wm*64+mi*16+l16][n0+wn*48+ni*16+lh*4+r] = acc[mi][ni][r]
  const int rowt = m0 + wm * 64 + l16;
#pragma unroll
  for (int ni = 0; ni < 3; ++ni) {
    const int gc0 = n0 + wn * 48 + ni * 16 + lh * 4;  // 16-col fragment never
    const int z = gc0 >> 10;                          // straddles a 1024 boundary
    const int lc = gc0 & 1023;
    if (z < 2) {
      u16* C = Qb + (long)z * 8388608;
#pragma unroll
      for (int mi = 0; mi < 4; ++mi) {
        u16x4 o;
#pragma unroll
        for (int r = 0; r < 4; ++r) o[r] = f2bf(acc[mi][ni][r]);
        *reinterpret_cast<u16x4*>(&C[(long)(rowt + mi * 16) * 1024 + lc]) = o;
      }
    } else {
      // V: Vt[b][e][t] = acc value at t = global row, e = lc + r.
#pragma unroll
      for (int mi = 0; mi < 4; ++mi) {
        const int grow = rowt + mi * 16;
        const int b = grow >> 11, t = grow & 2047;
#pragma unroll
        for (int r = 0; r < 4; ++r)
          Vt[(long)b * 2097152 + (long)(lc + r) * 2048 + t] = f2bf(acc[mi][ni][r]);
      }
    }
  }
}

// ---------------- S = exp(Q K^T): 64x128 tiles, BK=64, 3 blocks/CU (r13) ----------------
// r12 post-mortem: BK=32@3/CU null (doubled barriers canceled packing gain).
// This keeps the PROVEN BK=64 2-barrier step and fixes distribution instead:
// 1088 equal half-size blocks (64 q-rows x 128 k-cols), 48KB LDS -> 3/CU
// (768 slots, 1.42 rounds). kc->XCD affinity with balanced pairing: XCD x
// owns kc in {x, 15-x} (34 tiles/batch each) -> its K-panels (2MB) stay
// L2-resident; per-XCD block count equal.
// 4 waves, each 64x32 (acc[4][2], swapped operands). Same swizzles as QKV.
// Epilogue: P = exp(S) (0 above diagonal), bf16 store + row-sum atomics.
__global__ __launch_bounds__(256, 3) void gemm_s(const u16* __restrict__ Qb,
                                                 const u16* __restrict__ Kb,
                                                 u16* __restrict__ Sg,
                                                 float* __restrict__ Sums) {
  const int id = blockIdx.x;            // 0..1087
  const int x = id & 7;                 // XCD (round-robin assumption)
  const int q = id >> 3;                // 0..135
  const int bz = q / 34;
  int u = q - bz * 34;
  int qr, kc;
  const int n1 = 32 - 2 * x;            // tiles with kc = x  (qr = 2x..31)
  if (u < n1) { kc = x;      qr = 2 * x + u; }
  else        { kc = 15 - x; qr = 30 - 2 * x + (u - n1); }
  const int m0 = qr * 64, n0 = kc * 128;
  const int K = 1024;

  const u16* A = Qb + (long)bz * 2097152;
  const u16* B = Kb + (long)bz * 2097152;

  __shared__ u16 ldsA[2][4096];    // 64 x 64
  __shared__ u16 ldsB[2][8192];    // 128 x 64

  const int tid = threadIdx.x;          // 0..255
  const int lane = tid & 63;
  const int wn = tid >> 6;              // wave 0..3 owns cols wn*32..wn*32+31
  const int l16 = lane & 15, lh = lane >> 4;
  const int strow = tid >> 3;                       // 0..31
  const int scol = ((tid & 7) ^ (strow & 7)) * 8;   // pre-swizzled source col
  const int rsw = l16 & 7;                          // read-side swizzle key

  f32x4 acc[4][2];
#pragma unroll
  for (int mi = 0; mi < 4; ++mi)
#pragma unroll
    for (int ni = 0; ni < 2; ++ni) acc[mi][ni] = (f32x4)(0.0f);

  // stage: A 64x64 (2 issues of 32 rows), B 128x64 (4 issues)
  auto stage = [&](int d, int k0) {
#pragma unroll
    for (int l = 0; l < 2; ++l)
      gload_lds16(A + (long)(m0 + l * 32 + strow) * K + k0 + scol,
                  &ldsA[d][l * 2048 + tid * 8]);
#pragma unroll
    for (int l = 0; l < 4; ++l)
      gload_lds16(B + (long)(n0 + l * 32 + strow) * K + k0 + scol,
                  &ldsB[d][l * 2048 + tid * 8]);
  };

  stage(0, 0);
  int cur = 0;
  for (int k0 = 0; k0 < K; k0 += 64) {
    __syncthreads();                          // buf[cur] ready; old readers done
    if (k0 + 64 < K) stage(cur ^ 1, k0 + 64); // lands during compute below
#pragma unroll
    for (int kk = 0; kk < 2; ++kk) {
      bf16x8 af[4], bfr[2];
#pragma unroll
      for (int mi = 0; mi < 4; ++mi)
        af[mi] = *reinterpret_cast<const bf16x8*>(
            &ldsA[cur][(mi * 16 + l16) * 64 + (((kk * 4 + lh) ^ rsw)) * 8]);
#pragma unroll
      for (int ni = 0; ni < 2; ++ni)
        bfr[ni] = *reinterpret_cast<const bf16x8*>(
            &ldsB[cur][(wn * 32 + ni * 16 + l16) * 64 + (((kk * 4 + lh) ^ rsw)) * 8]);
#pragma unroll
      for (int mi = 0; mi < 4; ++mi)
#pragma unroll
        for (int ni = 0; ni < 2; ++ni)
          acc[mi][ni] = __builtin_amdgcn_mfma_f32_16x16x32_bf16(bfr[ni], af[mi], acc[mi][ni], 0, 0, 0);
    }
    cur ^= 1;
  }

  // P = exp(S), zero above diagonal; row sums from bf16-rounded values so
  // numerator/denominator agree. shfl over lh then 1 atomic per 16 lanes.
  // Swapped layout: C[m0+mi*16+l16][n0+wn*32+ni*16+lh*4+r]
  u16* C = Sg + (long)bz * 4194304;
  float* sums = Sums + (long)bz * 2048;
  const int coln = n0 + wn * 32 + lh * 4;
#pragma unroll
  for (int mi = 0; mi < 4; ++mi) {
    const int gr = m0 + mi * 16 + l16;
    float rs = 0.0f;
#pragma unroll
    for (int ni = 0; ni < 2; ++ni) {
      u16x4 o;
#pragma unroll
      for (int r = 0; r < 4; ++r) {
        const int gc = coln + ni * 16 + r;
        const float e = (gc <= gr) ? __expf(acc[mi][ni][r]) : 0.0f;
        const u16 ub = f2bf(e);
        o[r] = ub;
        rs += bf2f(ub);
      }
      *reinterpret_cast<u16x4*>(&C[(long)gr * 2048 + coln + ni * 16]) = o;
    }
    rs += __shfl_xor(rs, 16);
    rs += __shfl_xor(rs, 32);
    if (lh == 0) atomicAdd(&sums[gr], rs);
  }
}

// ---------------- PV GEMM: 128x128, 8 waves, balanced pairing (r13) ----------------
// bn = XCD -> each XCD streams one Vt panel (2MB, L2-resident).
// Long/short bm pairing: f = (q^(q>>5))&1 flips between the two co-residency
// candidates under BOTH plausible CU-fill orders (q vs q+32 sequential, or
// 2c vs 2c+1 paired), and i5 keeps bm-base equal within a pair -> every CU
// hosts bm=b and bm=15-b: exactly 17 K-steps per CU.
__global__ __launch_bounds__(512, 2) void gemm_pv(const u16* __restrict__ Ag,
                                                  const u16* __restrict__ Bg,
                                                  float* __restrict__ Cg,
                                                  const float* __restrict__ Sums) {
  const int id = blockIdx.x;            // 0..511
  const int x = id & 7;                 // XCD; also bn
  const int q = id >> 3;                // 0..63
  const int f = (q ^ (q >> 5)) & 1;
  const int i5 = ((q >> 1) & 15) | (((q >> 5) & 1) << 4);
  const int bmb = i5 & 7;
  const int bz = (i5 >> 3) & 3;
  const int bm = f ? (15 - bmb) : bmb;
  const int bn = x;
  const int K = 2048;

  const u16* A = Ag + (long)bz * 4194304;
  const u16* B = Bg + (long)bz * 2097152;
  const int m0 = bm * 128, n0 = bn * 128;
  const int kEnd = m0 + 128;

  __shared__ u16 ldsA[2][8192];
  __shared__ u16 ldsB[2][8192];

  const int tid = threadIdx.x;          // 0..511
  const int lane = tid & 63;
  const int wid = tid >> 6;             // 0..7
  const int wm = wid >> 2, wn = wid & 3;
  const int l16 = lane & 15, lh = lane >> 4;
  const int strow = tid >> 3;                       // 0..63
  const int scol = ((tid & 7) ^ (strow & 7)) * 8;   // pre-swizzled source column
  const int rsw = l16 & 7;                          // read-side swizzle key

  f32x4 acc[4][2];
#pragma unroll
  for (int mi = 0; mi < 4; ++mi)
#pragma unroll
    for (int ni = 0; ni < 2; ++ni) acc[mi][ni] = (f32x4)(0.0f);

  auto stage = [&](int d, int k0) {
#pragma unroll
    for (int l = 0; l < 2; ++l) {
      const int row = l * 64 + strow;   // 0..127
      gload_lds16(A + (long)(m0 + row) * K + k0 + scol, &ldsA[d][l * 4096 + tid * 8]);
      gload_lds16(B + (long)(n0 + row) * K + k0 + scol, &ldsB[d][l * 4096 + tid * 8]);
    }
  };

  stage(0, 0);
  int cur = 0;
  for (int k0 = 0; k0 < kEnd; k0 += 64) {
    __syncthreads();                         // buf[cur] ready; old readers done
    if (k0 + 64 < kEnd) stage(cur ^ 1, k0 + 64);  // lands during compute below
#pragma unroll
    for (int kk = 0; kk < 2; ++kk) {
      bf16x8 af[4], bfr[2];
#pragma unroll
      for (int mi = 0; mi < 4; ++mi)
        af[mi] = *reinterpret_cast<const bf16x8*>(
            &ldsA[cur][(wm * 64 + mi * 16 + l16) * 64 + (((kk * 4 + lh) ^ rsw)) * 8]);
#pragma unroll
      for (int ni = 0; ni < 2; ++ni)
        bfr[ni] = *reinterpret_cast<const bf16x8*>(
            &ldsB[cur][(wn * 32 + ni * 16 + l16) * 64 + (((kk * 4 + lh) ^ rsw)) * 8]);
#pragma unroll
      for (int mi = 0; mi < 4; ++mi)
#pragma unroll
        for (int ni = 0; ni < 2; ++ni)
          acc[mi][ni] = __builtin_amdgcn_mfma_f32_16x16x32_bf16(bfr[ni], af[mi], acc[mi][ni], 0, 0, 0);
    }
    cur ^= 1;
  }

  // O = acc / rowsum
  float* C = Cg + (long)bz * 2097152;
  const float* sums = Sums + (long)bz * 2048;
  const long rown = (long)(m0 + wm * 64 + l16);
  const int coln = n0 + wn * 32 + lh * 4;
#pragma unroll
  for (int mi = 0; mi < 4; ++mi) {
    const float inv = 1.0f / sums[(int)rown + mi * 16];
#pragma unroll
    for (int ni = 0; ni < 2; ++ni) {
      f32x4 v = acc[mi][ni] * inv;
      *reinterpret_cast<f32x4*>(&C[(rown + mi * 16) * 1024 + coln + ni * 16]) = v;
    }
  }
}

extern "C" void kernel_launch(void* const* d_in, const int* in_sizes, int n_in,
                              void* d_out, int out_size, void* d_ws, size_t ws_size,
                              hipStream_t stream) {
  const float* X  = (const float*)d_in[0];
  const float* Wq = (const float*)d_in[1];
  const float* Wk = (const float*)d_in[2];
  const float* Wv = (const float*)d_in[3];

  // workspace layout (u16 elements)
  u16* Xb = (u16*)d_ws;                 // 8192*1024
  u16* Wt = Xb + 8388608;               // [3072][1024]; Wq rows pre-scaled 1/32
  u16* Qb = Wt + 3145728;               // 8192*1024 (K follows at Qb+8388608)
  u16* Kb = Qb + 8388608;               // 8192*1024
  u16* Vt = Kb + 8388608;               // [b][1024][2048]
  u16* S  = Vt + 8388608;               // [b][2048][2048] -> holds P = exp(scores)
  float* sums = (float*)(S + 16777216); // [b][2048] row sums (32 KB)

  hipMemsetAsync(sums, 0, 4 * 2048 * sizeof(float), stream);

  // cast X + transpose W (one dispatch)
  prep_kernel<<<4864, 256, 0, stream>>>(X, Wq, Wk, Wv, Xb, Wt);

  // fused QKV projection, 128x192 tile (V written transposed); 1024 blocks = 2 rounds
  gemm_qkv<<<1024, 512, 0, stream>>>(Xb, Wt, Qb, Vt);

  // P = exp(Q K^T): 1088 64x128 tiles, 3/CU, kc->XCD affinity
  gemm_s<<<1088, 256, 0, stream>>>(Qb, Kb, S, sums);

  // O = P V / rowsum: bn=XCD, long/short bm pairing -> 17 K-steps per CU
  gemm_pv<<<512, 512, 0, stream>>>(S, Vt, (float*)d_out, sums);
}